// Round 9
// baseline (222.654 us; speedup 1.0000x reference)
//
#include <hip/hip_runtime.h>
#include <hip/hip_bf16.h>

typedef __bf16 bf16;
typedef __attribute__((ext_vector_type(8))) __bf16 bf16x8;
typedef __attribute__((ext_vector_type(4))) __bf16 bf16x4;
typedef __attribute__((ext_vector_type(4))) float f32x4;

#define TSEQ 2048
#define DMODEL 1024
#define NHEAD 16
#define DKH 64
#define BATCH 2
#define NQKV 3072
#define PSTR 72   // P-tile LDS stride (144B rows: 16B-aligned, conflict-free)

// async global->LDS, 16B per lane; LDS dest = wave-uniform base + lane*16
typedef __attribute__((address_space(1))) const void gv_t;
typedef __attribute__((address_space(3))) void sv_t;
__device__ __forceinline__ void gll16(const bf16* g, bf16* s) {
    __builtin_amdgcn_global_load_lds((gv_t*)g, (sv_t*)s, 16, 0, 0);
}
// s_waitcnt vmcnt(0) only — compiler does NOT associate pending LDS-DMA with
// s_barrier in pipelined loops (round-6 race); keep this before each barrier.
__device__ __forceinline__ void wait_vm0() {
    __builtin_amdgcn_s_waitcnt(0x0F70);
}

// ------------------------------------------------------------- fp32 -> bf16
__global__ __launch_bounds__(256) void convert_bf16(
    const float* __restrict__ in, bf16* __restrict__ out)
{
    int i = (blockIdx.x * 256 + threadIdx.x) * 4;
    f32x4 v = *(const f32x4*)(in + i);
    bf16x4 o;
#pragma unroll
    for (int j = 0; j < 4; ++j) o[j] = (bf16)v[j];
    *(bf16x4*)(out + i) = o;
}

// ------------------------------------------------------------- bias concat
__global__ __launch_bounds__(256) void bias_concat(
    const float* __restrict__ bq, const float* __restrict__ bk,
    const float* __restrict__ bv, float* __restrict__ out)
{
    int i = blockIdx.x * 256 + threadIdx.x; // 0..3071
    float v = i < 1024 ? bq[i] : i < 2048 ? bk[i - 1024] : bv[i - 2048];
    out[i] = v;
}

// ---------------------------------------------------------------- transpose W
__global__ __launch_bounds__(256) void transpose_w(
    const float* __restrict__ W0, const float* __restrict__ W1,
    const float* __restrict__ W2, const float* __restrict__ W3,
    bf16* __restrict__ WT)
{
    __shared__ float t[32][33];
    const float* W = blockIdx.z == 0 ? W0 : blockIdx.z == 1 ? W1
                   : blockIdx.z == 2 ? W2 : W3;
    bf16* T = WT + (size_t)blockIdx.z * DMODEL * DMODEL;
    int bx = blockIdx.x * 32, by = blockIdx.y * 32;
    int tx = threadIdx.x, ty = threadIdx.y;
#pragma unroll
    for (int i = 0; i < 4; ++i)
        t[ty + i * 8][tx] = W[(size_t)(by + ty + i * 8) * DMODEL + bx + tx];
    __syncthreads();
#pragma unroll
    for (int i = 0; i < 4; ++i)
        T[(size_t)(bx + ty + i * 8) * DMODEL + by + tx] = (bf16)t[tx][ty + i * 8];
}

// ---------------------------------------------------------------- GEMM + bias
// m97-style gll staging. For the QKV GEMM (Vout != null), blocks with
// n0 >= 2048 write their tile directly into V^T[b][h][d][t] layout with
// packed b64 stores (consecutive C-regs r = consecutive t) — this replaces
// the standalone transpose_v kernel.
template <typename OutT>
__global__ __launch_bounds__(256) void gemm_bias_kernel(
    const bf16* __restrict__ A, const bf16* __restrict__ BT,
    const float* __restrict__ bias, OutT* __restrict__ C, int ldc,
    bf16* __restrict__ Vout)
{
    __shared__ bf16 As[128 * 32];
    __shared__ bf16 Bs[128 * 32];
    const int tid = threadIdx.x;
    const int ln = tid & 63, wave = tid >> 6;
    const int wm = wave >> 1, wn = wave & 1;
    const int lr = ln & 15, quad = ln >> 4;
    const int m0 = blockIdx.y * 128, n0 = blockIdx.x * 128;

    f32x4 acc[4][4] = {};

    const int grow = wave * 32 + (ln >> 2);
    const int gcol = (ln & 3) * 8;
    const bf16* Ag = A + (size_t)(m0 + grow) * DMODEL + gcol;
    const bf16* Bg = BT + (size_t)(n0 + grow) * DMODEL + gcol;
    bf16* AsW = As + wave * 1024;
    bf16* BsW = Bs + wave * 1024;

    for (int kt = 0; kt < DMODEL / 32; ++kt) {
        const int kk = kt * 32;
#pragma unroll
        for (int l = 0; l < 2; ++l) {
            gll16(Ag + (size_t)(l * 16) * DMODEL + kk, AsW + l * 512);
            gll16(Bg + (size_t)(l * 16) * DMODEL + kk, BsW + l * 512);
        }
        wait_vm0();
        __syncthreads();
        bf16x8 af[4], bfr[4];
#pragma unroll
        for (int i = 0; i < 4; ++i)
            af[i] = *(const bf16x8*)(As + (wm * 64 + i * 16 + lr) * 32 + quad * 8);
#pragma unroll
        for (int j = 0; j < 4; ++j)
            bfr[j] = *(const bf16x8*)(Bs + (wn * 64 + j * 16 + lr) * 32 + quad * 8);
#pragma unroll
        for (int i = 0; i < 4; ++i)
#pragma unroll
            for (int j = 0; j < 4; ++j)
                acc[i][j] = __builtin_amdgcn_mfma_f32_16x16x32_bf16(
                    af[i], bfr[j], acc[i][j], 0, 0, 0);
        __syncthreads();
    }

    if (Vout != nullptr && n0 >= 2048) {
        // V-mode: write V^T[b][h*64+d][t] ; t = m (within batch), block-uniform
        const int bb = m0 >> 11;                 // batch index
        const int tb_ = (m0 & (TSEQ - 1)) + wm * 64;
#pragma unroll
        for (int j = 0; j < 4; ++j) {
            int n = n0 + wn * 64 + j * 16 + lr;
            int hd = n - 2048;                   // h*64+d
            float bv = bias[n];
            bf16* vrow = Vout + ((size_t)(bb * DMODEL + hd)) * TSEQ;
#pragma unroll
            for (int i = 0; i < 4; ++i) {
                int t = tb_ + i * 16 + quad * 4;
                bf16x4 v4;
#pragma unroll
                for (int r = 0; r < 4; ++r) v4[r] = (bf16)(acc[i][j][r] + bv);
                *(bf16x4*)(vrow + t) = v4;
            }
        }
    } else {
#pragma unroll
        for (int j = 0; j < 4; ++j) {
            int n = n0 + wn * 64 + j * 16 + lr;
            float bv = bias[n];
#pragma unroll
            for (int i = 0; i < 4; ++i) {
                int mb = m0 + wm * 64 + i * 16 + quad * 4;
#pragma unroll
                for (int r = 0; r < 4; ++r)
                    C[(size_t)(mb + r) * ldc + n] = (OutT)(acc[i][j][r] + bv);
            }
        }
    }
}

// ---------------------------------------------------------------- flash attn
// 4 waves x 32 q-rows = 128 rows/block. K/V 64-key tiles double-buffered via
// global_load_lds (XOR swizzle, stride 64), one barrier per chunk with
// explicit vmcnt drain. Fixed-max softmax (M=24 in exp2 domain). Each K/V
// ds_read_b128 feeds 2 MFMAs (32 rows/wave) — halves LDS-pipe traffic/row.
template <bool MASK>
__device__ __forceinline__ void attn_chunk(
    int kc, int q0w, int lr, int quad,
    const bf16* __restrict__ KsB, const bf16* __restrict__ VsB,
    bf16* __restrict__ Pw,
    const bf16x8 qb[2][2], f32x4 oacc[2][4], float lrow[2])
{
    const int sw = lr & 7; // row&7 for swizzled K/V reads
    // ---- S^T[key][q]: A=K-frag (LDS, swizzled), B=Q-frag (regs)
    bf16x8 kb[4][2];
#pragma unroll
    for (int kt = 0; kt < 4; ++kt)
#pragma unroll
        for (int kk = 0; kk < 2; ++kk)
            kb[kt][kk] = *(const bf16x8*)(KsB + (kt * 16 + lr) * 64 +
                                          (((kk * 4 + quad) ^ sw) * 8));
    f32x4 st[4][2] = {};
#pragma unroll
    for (int kt = 0; kt < 4; ++kt)
#pragma unroll
        for (int qt = 0; qt < 2; ++qt)
#pragma unroll
            for (int kk = 0; kk < 2; ++kk)
                st[kt][qt] = __builtin_amdgcn_mfma_f32_16x16x32_bf16(
                    kb[kt][kk], qb[qt][kk], st[kt][qt], 0, 0, 0);

    // ---- fixed-max softmax; lane lr owns q-rows q0w+qt*16+lr
    const float scale2 = 0.18033688f; // 0.125 * log2(e)
#pragma unroll
    for (int qt = 0; qt < 2; ++qt) {
        const int q = q0w + qt * 16 + lr;
        float rs = 0.f;
#pragma unroll
        for (int kt = 0; kt < 4; ++kt) {
            bf16x4 p4;
#pragma unroll
            for (int r = 0; r < 4; ++r) {
                float p = exp2f(fmaf(st[kt][qt][r], scale2, -24.0f));
                if (MASK && (kc + kt * 16 + quad * 4 + r > q)) p = 0.f;
                rs += p;
                p4[r] = (bf16)p;
            }
            *(bf16x4*)(Pw + (qt * 16 + lr) * PSTR + kt * 16 + quad * 4) = p4;
        }
        rs += __shfl_xor(rs, 16);
        rs += __shfl_xor(rs, 32);
        lrow[qt] += rs;
    }

    // ---- O += P V : A=P (per-wave LDS, unswizzled), B=V^T (LDS, swizzled)
#pragma unroll
    for (int kk = 0; kk < 2; ++kk) {
        bf16x8 pa0 = *(const bf16x8*)(Pw + (0 * 16 + lr) * PSTR + kk * 32 + quad * 8);
        bf16x8 pa1 = *(const bf16x8*)(Pw + (1 * 16 + lr) * PSTR + kk * 32 + quad * 8);
#pragma unroll
        for (int dt = 0; dt < 4; ++dt) {
            bf16x8 vb = *(const bf16x8*)(VsB + (dt * 16 + lr) * 64 +
                                         (((kk * 4 + quad) ^ sw) * 8));
            oacc[0][dt] = __builtin_amdgcn_mfma_f32_16x16x32_bf16(
                pa0, vb, oacc[0][dt], 0, 0, 0);
            oacc[1][dt] = __builtin_amdgcn_mfma_f32_16x16x32_bf16(
                pa1, vb, oacc[1][dt], 0, 0, 0);
        }
    }
}

__global__ __launch_bounds__(256) void flash_attn(
    const bf16* __restrict__ QKV, const bf16* __restrict__ VT,
    bf16* __restrict__ O)
{
    __shared__ bf16 Ks[2][64 * 64];
    __shared__ bf16 Vs[2][64 * 64];
    __shared__ bf16 Pl[4][32 * PSTR];
    const int tid = threadIdx.x;
    const int ln = tid & 63, w = tid >> 6;       // 4 waves
    const int lr = ln & 15, quad = ln >> 4;
    const int h = blockIdx.y, b = blockIdx.z;

    int xb = blockIdx.x;
    if ((h ^ b) & 1) xb = (TSEQ / 128 - 1) - xb; // big/small block interleave
    const int q0 = xb * 128;
    const int q0w = q0 + w * 32;                 // this wave's 32 rows
    bf16* Pw = Pl[w];

    const bf16* Qb = QKV + (size_t)b * TSEQ * NQKV + h * DKH;
    const bf16* Kb = Qb + 1024;
    const bf16* VTb = VT + (size_t)(b * NHEAD + h) * DKH * TSEQ;

    // staging: waves 0,1 -> K rows (w&1)*32..+31 ; waves 2,3 -> V rows same.
    // lane ln covers row +ln/8, 16B chunk (ln%8)^(row&7)  [XOR swizzle]
    const int srow = (w & 1) * 32 + (ln >> 3);
    const int scol = ((ln & 7) ^ ((ln >> 3) & 7)) * 8;
    const bool stK = (w < 2);

    auto stage = [&](int buf, int kc) {
        if (stK) {
            const bf16* g = Kb + (size_t)(kc + srow) * NQKV + scol;
            bf16* s = &Ks[buf][(w & 1) * 32 * 64];
#pragma unroll
            for (int l = 0; l < 4; ++l)
                gll16(g + (size_t)(l * 8) * NQKV, s + l * 8 * 64);
        } else {
            const bf16* g = VTb + (size_t)srow * TSEQ + kc + scol;
            bf16* s = &Vs[buf][(w & 1) * 32 * 64];
#pragma unroll
            for (int l = 0; l < 4; ++l)
                gll16(g + (size_t)(l * 8) * TSEQ, s + l * 8 * 64);
        }
    };

    // Q B-frags (persistent registers)
    bf16x8 qb[2][2];
#pragma unroll
    for (int qt = 0; qt < 2; ++qt)
#pragma unroll
        for (int kk = 0; kk < 2; ++kk)
            qb[qt][kk] = *(const bf16x8*)(Qb +
                (size_t)(q0w + qt * 16 + lr) * NQKV + kk * 32 + quad * 8);

    f32x4 oacc[2][4] = {};
    float lrow[2] = {0.f, 0.f};

    const int nch = (q0 + 128) >> 6;
    stage(0, 0);
    wait_vm0();
    __syncthreads();
    for (int c = 0; c < nch; ++c) {
        if (c + 1 < nch) stage((c + 1) & 1, (c + 1) * 64); // async prefetch
        const int kc = c * 64;
        if (kc <= q0w + 31) {
            if (kc + 63 <= q0w)
                attn_chunk<false>(kc, q0w, lr, quad, Ks[c & 1], Vs[c & 1], Pw,
                                  qb, oacc, lrow);
            else
                attn_chunk<true>(kc, q0w, lr, quad, Ks[c & 1], Vs[c & 1], Pw,
                                 qb, oacc, lrow);
        }
        wait_vm0();      // drain prefetch (overlapped with compute above)
        __syncthreads();
    }

    // ---- epilogue: divide by l (shuffle-broadcast), write O
#pragma unroll
    for (int qt = 0; qt < 2; ++qt)
#pragma unroll
        for (int r = 0; r < 4; ++r) {
            float inv = 1.0f / __shfl(lrow[qt], quad * 4 + r);
            int row = q0w + qt * 16 + quad * 4 + r;
#pragma unroll
            for (int dt = 0; dt < 4; ++dt)
                O[(size_t)(b * TSEQ + row) * DMODEL + h * DKH + dt * 16 + lr] =
                    (bf16)(oacc[qt][dt][r] * inv);
        }
}

// ---------------------------------------------------------------- launch
extern "C" void kernel_launch(void* const* d_in, const int* in_sizes, int n_in,
                              void* d_out, int out_size, void* d_ws, size_t ws_size,
                              hipStream_t stream)
{
    const float* x  = (const float*)d_in[0];
    const float* Wq = (const float*)d_in[2];
    const float* bq = (const float*)d_in[3];
    const float* Wk = (const float*)d_in[4];
    const float* bk = (const float*)d_in[5];
    const float* Wv = (const float*)d_in[6];
    const float* bv = (const float*)d_in[7];
    const float* Wo = (const float*)d_in[8];
    const float* bo = (const float*)d_in[9];

    char* ws = (char*)d_ws;
    bf16* xb   = (bf16*)(ws);                   // 8 MB
    bf16* QKV  = (bf16*)(ws + (8u  << 20));     // 24 MB [4096][3072] (Q,K live)
    bf16* VT   = (bf16*)(ws + (32u << 20));     // 8 MB [B][H][64][T] (GEMM-written)
    bf16* O    = (bf16*)(ws + (40u << 20));     // 8 MB (hosts QKV bias pre-flash)
    bf16* WT   = (bf16*)(ws + (48u << 20));     // 8 MB
    float* wsBias = (float*)O;                  // 12 KB; dead once flash writes O

    const int NX = BATCH * TSEQ * DMODEL;
    convert_bf16<<<NX / (256 * 4), 256, 0, stream>>>(x, xb);

    dim3 tb(32, 8);
    transpose_w<<<dim3(32, 32, 4), tb, 0, stream>>>(Wq, Wk, Wv, Wo, WT);
    bias_concat<<<NQKV / 256, 256, 0, stream>>>(bq, bk, bv, wsBias);

    // QKV projection; V columns go straight to VT (transposed), Q/K to QKV
    gemm_bias_kernel<bf16><<<dim3(NQKV / 128, 32), 256, 0, stream>>>(
        xb, WT, wsBias, QKV, NQKV, VT);

    flash_attn<<<dim3(TSEQ / 128, NHEAD, BATCH), 256, 0, stream>>>(QKV, VT, O);

    gemm_bias_kernel<float><<<dim3(DMODEL / 128, 32), 256, 0, stream>>>(
        O, WT + 3u * (1u << 20), bo, (float*)d_out, DMODEL, nullptr);
}